// Round 8
// baseline (253.087 us; speedup 1.0000x reference)
//
#include <hip/hip_runtime.h>
#include <math.h>

#define SB 1024   // seq len
#define DM 1024   // d_model
#define BB 4      // batch
#define NH 16     // heads
#define DH 64     // head dim
#define ML 1024   // MAX_LEN

typedef __attribute__((ext_vector_type(8))) short short8;
typedef __attribute__((ext_vector_type(8))) _Float16 half8;
typedef __attribute__((ext_vector_type(4))) float f32x4;
typedef unsigned short u16;

#define S_BARRIER() __builtin_amdgcn_s_barrier()
#define SCHED_FENCE() __builtin_amdgcn_sched_barrier(0)
#define WAITVL() asm volatile("s_waitcnt vmcnt(0) lgkmcnt(0)" ::: "memory")

__device__ __forceinline__ u16 f2bf(float x) {
  unsigned u = __float_as_uint(x);
  u += 0x7fffu + ((u >> 16) & 1u);
  return (u16)(u >> 16);
}
__device__ __forceinline__ float bf2f(u16 h) { return __uint_as_float((unsigned)h << 16); }

// async global->LDS, 16B per lane; lds base must be wave-uniform (HW adds lane*16)
__device__ __forceinline__ void async16(void* lds, const void* g) {
  __builtin_amdgcn_global_load_lds(
      (const __attribute__((address_space(1))) unsigned*)g,
      (__attribute__((address_space(3))) unsigned*)lds, 16, 0, 0);
}

// ======== S1: prep v2 (r17) — LDS-staged, coalesced-I/O packer ========
#define TPITCH 1028   // floats; %4==0 (16B align), %32==4 (bank spread)

__global__ __launch_bounds__(256, 4) void prep_all(
    const float* __restrict__ x, const float* __restrict__ gamma,
    const float* __restrict__ beta,
    const float* __restrict__ w_pos, const float* __restrict__ w_tok,
    _Float16* __restrict__ peH, _Float16* __restrict__ peL,
    _Float16* __restrict__ xnH, _Float16* __restrict__ xnL,
    _Float16* __restrict__ wpH, _Float16* __restrict__ wpL,
    _Float16* __restrict__ wtH, _Float16* __restrict__ wtL) {
  __shared__ float T[8 * TPITCH];      // 32.9 KB staging tile
  __shared__ float Sred[4][8][2];      // per-wave row stats (LN)

  int bid = blockIdx.x, t = threadIdx.x;
  int wv = t >> 6, lane = t & 63;

  int type, rt;
  const float* src = nullptr;
  _Float16 *dH, *dL;
  if (bid < 128)      { type = 0; rt = bid;       dH = peH; dL = peL; }
  else if (bid < 640) { type = 1; rt = bid - 128; src = x;     dH = xnH; dL = xnL; }
  else if (bid < 896) { type = 2; rt = bid - 640; src = w_pos; dH = wpH; dL = wpL; }
  else                { type = 2; rt = bid - 896; src = w_tok; dH = wtH; dL = wtL; }

  // ---- phase 1: fill T (coalesced: thread t covers cols t*4..+4 of each row)
  if (type == 0) {
    float div0 = exp2f((float)(t * 4)     * (-0.01297628162065376f));
    float div1 = exp2f((float)(t * 4 + 2) * (-0.01297628162065376f));
    #pragma unroll
    for (int i = 0; i < 8; ++i) {
      float p = (float)(rt * 8 + i);
      float a0 = p * div0, a1 = p * div1;
      float4 f;
      f.x = __sinf(a0); f.y = __cosf(a0);
      f.z = __sinf(a1); f.w = __cosf(a1);
      *(float4*)&T[i * TPITCH + t * 4] = f;
    }
  } else if (type == 1) {
    #pragma unroll
    for (int i = 0; i < 8; ++i) {
      float4 f = *(const float4*)(src + (size_t)(rt * 8 + i) * 1024 + t * 4);
      *(float4*)&T[i * TPITCH + t * 4] = f;
    }
  } else {
    #pragma unroll
    for (int i = 0; i < 8; ++i) {
      float4 f = *(const float4*)(src + (size_t)(rt * 8 + i) * 1024 + t * 4);
      f.x *= 32.f; f.y *= 32.f; f.z *= 32.f; f.w *= 32.f;
      *(float4*)&T[i * TPITCH + t * 4] = f;
    }
  }
  __syncthreads();

  // ---- phase 1b: LN row stats (thread: row t&7, 32-col chunk t>>3)
  if (type == 1) {
    int row = t & 7, cc = t >> 3;
    float s1 = 0.f, s2 = 0.f;
    #pragma unroll
    for (int i = 0; i < 8; ++i) {
      float4 f = *(const float4*)&T[row * TPITCH + cc * 32 + i * 4];
      s1 += f.x + f.y + f.z + f.w;
      s2 += f.x*f.x + f.y*f.y + f.z*f.z + f.w*f.w;
    }
    s1 += __shfl_xor(s1, 8, 64);  s2 += __shfl_xor(s2, 8, 64);
    s1 += __shfl_xor(s1, 16, 64); s2 += __shfl_xor(s2, 16, 64);
    s1 += __shfl_xor(s1, 32, 64); s2 += __shfl_xor(s2, 32, 64);
    if (lane < 8) { Sred[wv][lane][0] = s1; Sred[wv][lane][1] = s2; }
  }
  __syncthreads();

  // ---- phase 2: pack; lane l -> row l&7, col-group (l>>3)&3, kt-parity l>>5
  int row = lane & 7, gg = (lane >> 3) & 3, ktp = lane >> 5;
  float mu = 0.f, rs = 0.f;
  if (type == 1) {
    float s1 = Sred[0][row][0] + Sred[1][row][0] + Sred[2][row][0] + Sred[3][row][0];
    float s2 = Sred[0][row][1] + Sred[1][row][1] + Sred[2][row][1] + Sred[3][row][1];
    mu = s1 * (1.0f / 1024.0f);
    float var = s2 * (1.0f / 1024.0f) - mu * mu;
    rs = rsqrtf(var + 1e-5f);
  }
  int grow16 = rt >> 1;
  int rsub = (rt & 1) * 8 + row;
  #pragma unroll
  for (int q = 0; q < 4; ++q) {
    int kt = wv * 8 + q * 2 + ktp;
    int col = kt * 32 + gg * 8;
    float v[8];
    *(float4*)&v[0] = *(const float4*)&T[row * TPITCH + col];
    *(float4*)&v[4] = *(const float4*)&T[row * TPITCH + col + 4];
    if (type == 1) {
      float4 gp0 = *(const float4*)(gamma + col);
      float4 gp1 = *(const float4*)(gamma + col + 4);
      float4 bp0 = *(const float4*)(beta + col);
      float4 bp1 = *(const float4*)(beta + col + 4);
      v[0] = (v[0]-mu)*rs*gp0.x + bp0.x;  v[1] = (v[1]-mu)*rs*gp0.y + bp0.y;
      v[2] = (v[2]-mu)*rs*gp0.z + bp0.z;  v[3] = (v[3]-mu)*rs*gp0.w + bp0.w;
      v[4] = (v[4]-mu)*rs*gp1.x + bp1.x;  v[5] = (v[5]-mu)*rs*gp1.y + bp1.y;
      v[6] = (v[6]-mu)*rs*gp1.z + bp1.z;  v[7] = (v[7]-mu)*rs*gp1.w + bp1.w;
    }
    half8 hv, lv;
    #pragma unroll
    for (int j = 0; j < 8; ++j) {
      _Float16 h = (_Float16)v[j];
      hv[j] = h;
      lv[j] = (_Float16)(v[j] - (float)h);
    }
    size_t off = ((size_t)(grow16 * 32 + kt) * 64 + rsub + gg * 16) * 8;
    *(half8*)(dH + off) = hv;
    *(half8*)(dL + off) = lv;
  }
}

// ======== S2-fast: merged GEMM (r13 exact — best measured, 92us) ========
// NOTE (r14/r15 post-mortems): this kernel runs at ~794 TF = the 2-barrier
// K-step structure's ceiling. Explicit dbuf+counted-vmcnt (r14) = zero delta;
// staging B-lo via LDS (r15) = +17us regression. Do not re-attempt source-
// level pipelining on this structure.
__global__ __launch_bounds__(256, 2) void gemm16p(
    const _Float16* __restrict__ AtH, const _Float16* __restrict__ AtL,
    const _Float16* __restrict__ ApH, const _Float16* __restrict__ ApL,
    const _Float16* __restrict__ BtH, const _Float16* __restrict__ BtL,
    const _Float16* __restrict__ BpH, const _Float16* __restrict__ BpL,
    u16* __restrict__ KtfH, u16* __restrict__ KtfL,
    u16* __restrict__ KpfH, u16* __restrict__ KpfL,
    u16* __restrict__ QH, u16* __restrict__ QL,
    u16* __restrict__ pQH, u16* __restrict__ pQL,
    u16* __restrict__ vF, float sK, float sQ, float sV) {
  __shared__ _Float16 L[32 * 512];
  int t = threadIdx.x;
  int wv = t >> 6, lane = t & 63;
  int wm = wv >> 1, wn = wv & 1;
  int r16 = lane & 15, g = lane >> 4;

  int phys = blockIdx.x;
  int bid = (phys & 7) * 56 + (phys >> 3);   // XCD-chunked swizzle (448 = 8*56)
  bool isPos = (bid >= 384);
  int idx = isPos ? bid - 384 : bid;
  int n0, m0;
  const _Float16 *AH, *AL, *BH, *BL;
  if (isPos) { n0 = (idx & 7) * 256;  m0 = (idx >> 3) * 128;
               AH = ApH; AL = ApL; BH = BpH; BL = BpL; }
  else       { n0 = (idx % 12) * 256; m0 = (idx / 12) * 128;
               AH = AtH; AL = AtL; BH = BtH; BL = BtL; }
  int mt0 = m0 >> 4, nt0 = n0 >> 4;
  bool split = isPos || (n0 < 2048);   // tok V band (n0>=2048): hh-only

  f32x4 acc[4][8];
  #pragma unroll
  for (int i = 0; i < 4; ++i)
    #pragma unroll
    for (int j = 0; j < 8; ++j) acc[i][j] = (f32x4){0.f, 0.f, 0.f, 0.f};

  for (int kt = 0; kt < 32; ++kt) {
    __syncthreads();
    #pragma unroll
    for (int rd = 0; rd < 8; ++rd) {
      int ci = rd * 4 + wv;
      bool isAlo = (ci < 16) && (ci & 1);
      if (!split && isAlo) continue;         // wave-uniform skip
      const _Float16* src;
      if (ci < 16) {
        int mt = ci >> 1, pl = ci & 1;
        const _Float16* P = pl ? AL : AH;
        src = P + ((size_t)((mt0 + mt) * 32 + kt) * 64 + lane) * 8;
      } else {
        int nt = ci - 16;
        src = BH + ((size_t)((nt0 + nt) * 32 + kt) * 64 + lane) * 8;
      }
      async16(&L[ci * 512], src);
    }
    half8 blo[8];
    if (split) {
      #pragma unroll
      for (int j = 0; j < 8; ++j) {
        int ntg = nt0 + wn * 8 + j;
        blo[j] = *(const half8*)(BL + ((size_t)(ntg * 32 + kt) * 64 + lane) * 8);
      }
    }
    __syncthreads();

    half8 ah[4], al[4];
    #pragma unroll
    for (int i = 0; i < 4; ++i)
      ah[i] = *(const half8*)&L[(((wm * 4 + i) * 2 + 0) * 512) + lane * 8];
    if (split) {
      #pragma unroll
      for (int i = 0; i < 4; ++i)
        al[i] = *(const half8*)&L[(((wm * 4 + i) * 2 + 1) * 512) + lane * 8];
    }
    #pragma unroll
    for (int j = 0; j < 8; ++j) {
      half8 bh = *(const half8*)&L[((16 + wn * 8 + j) * 512) + lane * 8];
      #pragma unroll
      for (int i = 0; i < 4; ++i) {
        acc[i][j] = __builtin_amdgcn_mfma_f32_16x16x32_f16(ah[i], bh, acc[i][j], 0, 0, 0);
        if (split) {
          acc[i][j] = __builtin_amdgcn_mfma_f32_16x16x32_f16(al[i], bh, acc[i][j], 0, 0, 0);
          acc[i][j] = __builtin_amdgcn_mfma_f32_16x16x32_f16(ah[i], blo[j], acc[i][j], 0, 0, 0);
        }
      }
    }
  }

  int band = n0 >> 10;
  u16* fKH = isPos ? KpfH : KtfH;
  u16* fKL = isPos ? KpfL : KtfL;
  u16* qHo = isPos ? pQH  : QH;
  u16* qLo = isPos ? pQL  : QL;
  if (band == 1) {
    #pragma unroll
    for (int i = 0; i < 4; ++i)
      #pragma unroll
      for (int j = 0; j < 8; ++j) {
        int lc = (n0 & 1023) + wn * 128 + j * 16 + r16;
        #pragma unroll
        for (int reg = 0; reg < 4; ++reg) {
          int row = m0 + wm * 64 + i * 16 + g * 4 + reg;
          float cv = acc[i][j][reg] * sQ;
          u16 hi = f2bf(cv);
          qHo[(size_t)row * 1024 + lc] = hi;
          qLo[(size_t)row * 1024 + lc] = f2bf(cv - bf2f(hi));
        }
      }
  } else if (band == 0) {
    #pragma unroll
    for (int i = 0; i < 4; ++i)
      #pragma unroll
      for (int j = 0; j < 8; ++j) {
        int colg = n0 + wn * 128 + j * 16 + r16;   // < 1024
        int h = colg >> 6, dc = colg & 63;
        #pragma unroll
        for (int reg = 0; reg < 4; ++reg) {
          int row = m0 + wm * 64 + i * 16 + g * 4 + reg;
          int bhK = (row >> 10) * NH + h;
          size_t a = ((size_t)((bhK * 64 + ((row & 1023) >> 4)) * 2 + (dc >> 5)) << 9)
                   + ((row & 15) + 16 * ((dc >> 3) & 3)) * 8 + (dc & 7);
          float cv = acc[i][j][reg] * sK;
          u16 hi = f2bf(cv);
          fKH[a] = hi;
          fKL[a] = f2bf(cv - bf2f(hi));
        }
      }
  } else {
    #pragma unroll
    for (int i = 0; i < 4; ++i)
      #pragma unroll
      for (int j = 0; j < 8; ++j) {
        int colg = (n0 & 1023) + wn * 128 + j * 16 + r16;
        int h = colg >> 6, dc = colg & 63;
        #pragma unroll
        for (int reg = 0; reg < 4; ++reg) {
          int row = m0 + wm * 64 + i * 16 + g * 4 + reg;
          int s = row & 1023;
          size_t a = ((size_t)((((row >> 10) * NH + h) * 32 + (s >> 5)) * 4 + (dc >> 4)) << 9)
                   + ((s >> 3) & 3) * 128 + (s & 7) + (dc & 15) * 8;
          vF[a] = f2bf(acc[i][j][reg] * sV);
        }
      }
  }
}

// ======== S2-fallback: r12 merged GEMM, B staged from fp32 originals ========
__global__ __launch_bounds__(256, 2) void gemm16m(
    const _Float16* __restrict__ AtH, const _Float16* __restrict__ AtL,
    const _Float16* __restrict__ ApH, const _Float16* __restrict__ ApL,
    const float* __restrict__ Wt, const float* __restrict__ Wp,
    u16* __restrict__ KtfH, u16* __restrict__ KtfL,
    u16* __restrict__ KpfH, u16* __restrict__ KpfL,
    u16* __restrict__ QH, u16* __restrict__ QL,
    u16* __restrict__ pQH, u16* __restrict__ pQL,
    u16* __restrict__ vF, float sK, float sQ, float sV) {
  __shared__ _Float16 L[48 * 512];
  int t = threadIdx.x;
  int wv = t >> 6, lane = t & 63;
  int wm = wv >> 1, wn = wv & 1;
  int r16 = lane & 15, g = lane >> 4;

  int phys = blockIdx.x;
  int bid = (phys & 7) * 56 + (phys >> 3);   // XCD-chunked swizzle
  bool isPos = (bid >= 384);
  int idx = isPos ? bid - 384 : bid;
  int n0, m0;
  const _Float16 *AH, *AL;
  const float* W;
  if (isPos) { n0 = (idx & 7) * 256;  m0 = (idx >> 3) * 128; AH = ApH; AL = ApL; W = Wp; }
  else       { n0 = (idx % 12) * 256; m0 = (idx / 12) * 128; AH = AtH; AL = AtL; W = Wt; }
  int mt0 = m0 >> 4, nt0 = n0 >> 4;
  bool split = isPos || (n0 < 2048);

  f32x4 acc[4][8];
  #pragma unroll
  for (int i = 0; i < 4; ++i)
    #pragma unroll
    for (int j = 0; j < 8; ++j) acc[i][j] = (f32x4){0.f, 0.f, 0.f, 0.f};

  for (int kt = 0; kt < 32; ++kt) {
    __syncthreads();
    #pragma unroll
    for (int rd = 0; rd < 4; ++rd) {
      int ci = rd * 4 + wv;
      int mt = ci >> 1, pl = ci & 1;
      if (!split && pl) continue;
      const _Float16* src = (pl ? AL : AH)
          + ((size_t)((mt0 + mt) * 32 + kt) * 64 + lane) * 8;
      async16(&L[ci * 512], src);
    }
    #pragma unroll
    for (int tt = 0; tt < 4; ++tt) {
      int nt = wv * 4 + tt;
      const float* wsrc = W + (size_t)((nt0 + nt) * 16 + r16) * 1024 + kt * 32 + g * 8;
      float4 w0 = *(const float4*)wsrc;
      float4 w1 = *(const float4*)(wsrc + 4);
      float wvv[8] = {w0.x, w0.y, w0.z, w0.w, w1.x, w1.y, w1.z, w1.w};
      half8 hv, lv;
      #pragma unroll
      for (int j = 0; j < 8; ++j) {
        float xx = wvv[j] * 32.0f;
        _Float16 h = (_Float16)xx;
        hv[j] = h;
        lv[j] = (_Float16)(xx - (float)h);
      }
      *(half8*)&L[(16 + nt) * 512 + lane * 8] = hv;
      if (split) *(half8*)&L[(32 + nt) * 512 + lane * 8] = lv;
    }
    __syncthreads();

    half8 ah[4], al[4];
    #pragma unroll
    for (int i = 0; i < 4; ++i)
      ah[i] = *(const half8*)&L[(((wm * 4 + i) * 2 + 0) * 512) + lane * 8];
    if (split) {
      #pragma unroll
      for (int i = 0; i < 4; ++i)
        al[i] = *(const half8*)&L[(((wm * 4 + i) * 2 + 1) * 512) + lane * 8];
    }
    #pragma unroll
    for (int j = 0; j < 8; ++j) {
      half8 bh = *(const half8*)&L[((16 + wn * 8 + j) * 512) + lane * 8];
      #pragma unroll
      for (int i = 0; i < 4; ++i) {
        acc[i][j] = __builtin_amdgcn_mfma_f32_16x16x32_f16(ah[i], bh, acc[i][j], 0, 0, 0);
        if (split) {
          half8 bl = *(const half8*)&L[((32 + wn * 8 + j) * 512) + lane * 8];
          acc[i][j] = __builtin_amdgcn_mfma_f32_16x16x32_f16(al[i], bh, acc[i][j], 0, 0, 0);
          acc[i][j] = __builtin_amdgcn_mfma_f32_16x16x32_f16(ah[i], bl, acc[i][j], 0, 0, 0);
        }
      }
    }
  }

  int band = n0 >> 10;
  u16* fKH = isPos ? KpfH : KtfH;
  u16* fKL = isPos ? KpfL : KtfL;
  u16* qHo = isPos ? pQH  : QH;
  u16* qLo = isPos ? pQL  : QL;
  if (band == 1) {
    #pragma unroll
    for (int i = 0; i < 4; ++i)
      #pragma unroll
      for (int j = 0; j < 8; ++j) {
        int lc = (n0 & 1023) + wn * 128 + j * 16 + r16;
        #pragma unroll
        for (int reg = 0; reg < 4; ++reg) {
          int row = m0 + wm * 64 + i * 16 + g * 4 + reg;
          float cv = acc[i][j][reg] * sQ;
          u16 hi = f2bf(cv);
          qHo[(size_t)row * 1024 + lc] = hi;
          qLo[(size_t)row * 1024 + lc] = f2bf(cv - bf2f(hi));
        }
      }
  } else if (band == 0) {
    #pragma unroll
    for (int i = 0; i < 4; ++i)
      #pragma unroll
      for (int j = 0; j < 8; ++j) {
        int colg = n0 + wn * 128 + j * 16 + r16;
        int h = colg >> 6, dc = colg & 63;
        #pragma unroll
        for (int reg = 0; reg < 4; ++reg) {
          int row = m0 + wm * 64 + i * 16 + g * 4 + reg;
          int bhK = (row >> 10) * NH + h;
          size_t a = ((size_t)((bhK * 64 + ((row & 1023) >> 4)) * 2 + (dc >> 5)) << 9)
                   + ((row & 15) + 16 * ((dc >> 3) & 3)) * 8 + (dc & 7);
          float cv = acc[i][j][reg] * sK;
          u16 hi = f2bf(cv);
          fKH[a] = hi;
          fKL[a] = f2bf(cv - bf2f(hi));
        }
      }
  } else {
    #pragma unroll
    for (int i = 0; i < 4; ++i)
      #pragma unroll
      for (int j = 0; j < 8; ++j) {
        int colg = (n0 & 1023) + wn * 128 + j * 16 + r16;
        int h = colg >> 6, dc = colg & 63;
        #pragma unroll
        for (int reg = 0; reg < 4; ++reg) {
          int row = m0 + wm * 64 + i * 16 + g * 4 + reg;
          int s = row & 1023;
          size_t a = ((size_t)((((row >> 10) * NH + h) * 32 + (s >> 5)) * 4 + (dc >> 4)) << 9)
                   + ((s >> 3) & 3) * 128 + (s & 7) + (dc & 15) * 8;
          vF[a] = f2bf(acc[i][j][reg] * sV);
        }
      }
  }
}

// ======== S3: MFMA flash attention, r18 ========
// r17 post-mortem: attn is LDS-PIPE-bound (~44 ds_read_b128 + ~32 scalar LDS
// reads per wave per ktr; one LDS pipe per CU shared by 8 waves ~= 43us of the
// 85us). r18 cuts LDS traffic + destalls:
//  1. kp (pos-K) frags read from GLOBAL (L1/L2-hit: shared by 32 blocks, wave-
//     identical within block) -> -16 b128/wave/ktr, Klds drops to tok+V.
//  2. bias identity bias[1][nt] == bias[0][nt-1] -> 32 -> 20 scalar LDS reads.
//  3. true double-buffered Klds (2 x 24KB; total LDS 65KB, still 2 blocks/CU):
//     stage(t+1) issued right after the barrier, hidden under full compute;
//     loop-top vmcnt(0) is free (vs r13's exposed per-ktr drain).
__device__ __forceinline__ void stage_tv(u16* B,
    const u16* ktH, const u16* ktL, const u16* vb, int wv, int lo) {
  int p0 = wv * 512, p1 = (wv + 4) * 512;
  async16(&B[0 * 4096 + p0], ktH + p0 + lo);
  async16(&B[0 * 4096 + p1], ktH + p1 + lo);
  async16(&B[1 * 4096 + p0], ktL + p0 + lo);
  async16(&B[1 * 4096 + p1], ktL + p1 + lo);
  async16(&B[2 * 4096 + p0], vb + p0 + lo);
  async16(&B[2 * 4096 + p1], vb + p1 + lo);
}

__global__ __launch_bounds__(256, 2) void attn_mfma12(
    const u16* __restrict__ KtfH, const u16* __restrict__ KtfL,
    const u16* __restrict__ KpfH, const u16* __restrict__ KpfL,
    const u16* __restrict__ QHg, const u16* __restrict__ QLg,
    const u16* __restrict__ pQH, const u16* __restrict__ pQL,
    const u16* __restrict__ Vf,
    const float* __restrict__ bt,
    float* __restrict__ out) {
  __shared__ u16 Klds[2][3 * 4096];  // 48 KB: dbuf x [tokH|tokL|V]
  __shared__ float biasL[2 * ML];    // 8 KB
  __shared__ u16 Pb[4][16 * 72];     // 9 KB: per-wave P staging

  int phys = blockIdx.x;
  int bid = (phys & 7) * 64 + (phys >> 3);   // XCD-chunked (512 = 8*64, bijective)
  int qt = bid & 7;
  int bh = bid >> 3;
  int b = bh >> 4, h = bh & 15;
  int q0 = qt * 128;
  int t = threadIdx.x;
  int wv = t >> 6, lane = t & 63;
  int g = lane >> 4, r16 = lane & 15;
  int lo = lane * 8;                 // this lane's 16B frag offset (u16 units)

  #pragma unroll
  for (int k = 0; k < 8; ++k)
    biasL[t + k * 256] = bt[(size_t)(t + k * 256) * NH + h];

  short8 qhi[2][4], qlo[2][4];
  #pragma unroll
  for (int cc = 0; cc < 2; ++cc) {
    int qrow = q0 + wv * 32 + cc * 16 + r16;
    #pragma unroll
    for (int c = 0; c < 4; ++c) {
      if (c < 2) {
        size_t off = (size_t)(b * SB + qrow) * 1024 + h * DH + c * 32 + g * 8;
        qhi[cc][c] = *(const short8*)(QHg + off);
        qlo[cc][c] = *(const short8*)(QLg + off);
      } else {
        size_t off = (size_t)qrow * 1024 + h * DH + (c - 2) * 32 + g * 8;
        qhi[cc][c] = *(const short8*)(pQH + off);
        qlo[cc][c] = *(const short8*)(pQL + off);
      }
    }
  }

  f32x4 O[2][4];
  #pragma unroll
  for (int cc = 0; cc < 2; ++cc)
    #pragma unroll
    for (int dt = 0; dt < 4; ++dt) O[cc][dt] = (f32x4){0.f, 0.f, 0.f, 0.f};
  float m_run[2][4], l_run[2][4];
  #pragma unroll
  for (int cc = 0; cc < 2; ++cc)
    #pragma unroll
    for (int reg = 0; reg < 4; ++reg) { m_run[cc][reg] = -3e38f; l_run[cc][reg] = 0.f; }

  int qb0 = q0 + wv * 32 + g * 4;
  const u16* ktHb = KtfH + (size_t)(bh * 64) * 1024;
  const u16* ktLb = KtfL + (size_t)(bh * 64) * 1024;
  const u16* kpHb = KpfH + (size_t)(h * 64) * 1024 + lo;
  const u16* kpLb = KpfL + (size_t)(h * 64) * 1024 + lo;
  const u16* vb   = Vf   + (size_t)(bh * 32) * 2048;
  int bb = ML + r16 - qb0;

  // prologue: stage ktr=0 into buffer 0
  stage_tv(&Klds[0][0], ktHb, ktLb, vb, wv, lo);

  for (int ktr = 0; ktr < 16; ++ktr) {
    u16* buf = &Klds[ktr & 1][0];
    // stage(ktr) done (issued a full compute phase ago; ktr=0: prologue) and
    // biasL ds_writes drained; barrier also retires all reads of buf^1.
    WAITVL();
    S_BARRIER();
    SCHED_FENCE();
    if (ktr < 15)
      stage_tv(&Klds[(ktr + 1) & 1][0], ktHb + 4096, ktLb + 4096, vb + 4096, wv, lo);

    // bias: only 20 distinct values (bias[1][nt] == bias[0][nt-1] for nt>=1)
    float bias0[4][4], bias1[4];
    #pragma unroll
    for (int nt = 0; nt < 4; ++nt)
      #pragma unroll
      for (int reg = 0; reg < 4; ++reg)
        bias0[nt][reg] = biasL[bb + nt * 16 - reg];
    #pragma unroll
    for (int reg = 0; reg < 4; ++reg)
      bias1[reg] = biasL[bb - 16 - reg];

    f32x4 S[2][4];
    #pragma unroll
    for (int nt = 0; nt < 4; ++nt) {
      f32x4 a0 = (f32x4){0.f, 0.f, 0.f, 0.f};
      f32x4 a1 = (f32x4){0.f, 0.f, 0.f, 0.f};
      #pragma unroll
      for (int c = 0; c < 4; ++c) {
        int co = c & 1;
        short8 bhi, blo;
        if (c < 2) {
          bhi = *(const short8*)&buf[0 * 4096 + nt * 1024 + co * 512 + lo];
          blo = *(const short8*)&buf[1 * 4096 + nt * 1024 + co * 512 + lo];
        } else {
          bhi = *(const short8*)(kpHb + nt * 1024 + co * 512);
          blo = *(const short8*)(kpLb + nt * 1024 + co * 512);
        }
        a0 = __builtin_amdgcn_mfma_f32_16x16x32_bf16(qhi[0][c], bhi, a0, 0, 0, 0);
        a1 = __builtin_amdgcn_mfma_f32_16x16x32_bf16(qhi[1][c], bhi, a1, 0, 0, 0);
        a0 = __builtin_amdgcn_mfma_f32_16x16x32_bf16(qlo[0][c], bhi, a0, 0, 0, 0);
        a1 = __builtin_amdgcn_mfma_f32_16x16x32_bf16(qlo[1][c], bhi, a1, 0, 0, 0);
        a0 = __builtin_amdgcn_mfma_f32_16x16x32_bf16(qhi[0][c], blo, a0, 0, 0, 0);
        a1 = __builtin_amdgcn_mfma_f32_16x16x32_bf16(qhi[1][c], blo, a1, 0, 0, 0);
      }
      S[0][nt] = a0; S[1][nt] = a1;
    }

    short8 vfrag[2][4];
    #pragma unroll
    for (int kc = 0; kc < 2; ++kc)
      #pragma unroll
      for (int dt = 0; dt < 4; ++dt)
        vfrag[kc][dt] = *(const short8*)&buf[2 * 4096 + (kc * 4 + dt) * 512 + lo];

    #pragma unroll
    for (int nt = 0; nt < 4; ++nt)
      #pragma unroll
      for (int reg = 0; reg < 4; ++reg) {
        S[0][nt][reg] += bias0[nt][reg];
        S[1][nt][reg] += (nt == 0) ? bias1[reg] : bias0[nt - 1][reg];
      }

    float tm[2][4], al[2][4];
    #pragma unroll
    for (int cc = 0; cc < 2; ++cc)
      #pragma unroll
      for (int reg = 0; reg < 4; ++reg)
        tm[cc][reg] = fmaxf(fmaxf(S[cc][0][reg], S[cc][1][reg]),
                            fmaxf(S[cc][2][reg], S[cc][3][reg]));
    #pragma unroll
    for (int off = 1; off < 16; off <<= 1)
      #pragma unroll
      for (int cc = 0; cc < 2; ++cc)
        #pragma unroll
        for (int reg = 0; reg < 4; ++reg)
          tm[cc][reg] = fmaxf(tm[cc][reg], __shfl_xor(tm[cc][reg], off, 64));
    #pragma unroll
    for (int cc = 0; cc < 2; ++cc)
      #pragma unroll
      for (int reg = 0; reg < 4; ++reg) {
        float mn = fmaxf(m_run[cc][reg], tm[cc][reg]);
        al[cc][reg] = __expf(m_run[cc][reg] - mn);
        m_run[cc][reg] = mn;
      }
    float ts[2][4] = {{0.f, 0.f, 0.f, 0.f}, {0.f, 0.f, 0.f, 0.f}};
    #pragma unroll
    for (int cc = 0; cc < 2; ++cc)
      #pragma unroll
      for (int nt = 0; nt < 4; ++nt)
        #pragma unroll
        for (int reg = 0; reg < 4; ++reg) {
          float p = __expf(S[cc][nt][reg] - m_run[cc][reg]);
          S[cc][nt][reg] = p;
          ts[cc][reg] += p;
        }
    #pragma unroll
    for (int cc = 0; cc < 2; ++cc)
      #pragma unroll
      for (int reg = 0; reg < 4; ++reg)
        l_run[cc][reg] = l_run[cc][reg] * al[cc][reg] + ts[cc][reg];
    #pragma unroll
    for (int cc = 0; cc < 2; ++cc)
      #pragma unroll
      for (int dt = 0; dt < 4; ++dt)
        #pragma unroll
        for (int reg = 0; reg < 4; ++reg)
          O[cc][dt][reg] *= al[cc][reg];

    // P staging + PV, one cc at a time (per-wave in-order DS pipeline makes
    // write->read->rewrite safe without barriers)
    #pragma unroll
    for (int cc = 0; cc < 2; ++cc) {
      u16* pb = Pb[wv];
      #pragma unroll
      for (int nt = 0; nt < 4; ++nt)
        #pragma unroll
        for (int reg = 0; reg < 4; ++reg)
          pb[(g * 4 + reg) * 72 + nt * 16 + r16] = f2bf(S[cc][nt][reg]);
      #pragma unroll
      for (int kc = 0; kc < 2; ++kc) {
        short8 pa = *(const short8*)&Pb[wv][r16 * 72 + kc * 32 + g * 8];
        #pragma unroll
        for (int dt = 0; dt < 4; ++dt)
          O[cc][dt] = __builtin_amdgcn_mfma_f32_16x16x32_bf16(pa, vfrag[kc][dt], O[cc][dt], 0, 0, 0);
      }
    }

    ktHb += 4096; ktLb += 4096; kpHb += 4096; kpLb += 4096;
    vb += 4096; bb += 64;
  }

  #pragma unroll
  for (int off = 1; off < 16; off <<= 1)
    #pragma unroll
    for (int cc = 0; cc < 2; ++cc)
      #pragma unroll
      for (int reg = 0; reg < 4; ++reg)
        l_run[cc][reg] += __shfl_xor(l_run[cc][reg], off, 64);
  #pragma unroll
  for (int cc = 0; cc < 2; ++cc)
    #pragma unroll
    for (int reg = 0; reg < 4; ++reg) l_run[cc][reg] = 1.0f / l_run[cc][reg];
  #pragma unroll
  for (int cc = 0; cc < 2; ++cc)
    #pragma unroll
    for (int dt = 0; dt < 4; ++dt)
      #pragma unroll
      for (int reg = 0; reg < 4; ++reg)
        out[(size_t)(b * SB + qb0 + cc * 16 + reg) * DM + h * DH + dt * 16 + r16] =
            O[cc][dt][reg] * l_run[cc][reg];
}

extern "C" void kernel_launch(void* const* d_in, const int* in_sizes, int n_in,
                              void* d_out, int out_size, void* d_ws, size_t ws_size,
                              hipStream_t stream) {
  const float* x     = (const float*)d_in[0];
  const float* gamma = (const float*)d_in[1];
  const float* beta  = (const float*)d_in[2];
  const float* w_pos = (const float*)d_in[3];
  const float* w_tok = (const float*)d_in[4];
  const float* bt    = (const float*)d_in[5];
  float* out = (float*)d_out;
  float* ws  = (float*)d_ws;
  const size_t M1 = 1u << 20;
  const float IS = 11.313708498984761f;  // sqrt(2*dh)

  u16 *KtfH, *KtfL, *KpfH, *KpfL, *QH, *QL, *posQH, *posQL, *Vf;

  if (ws_size >= 22 * M1 * 4) {
    // ---- FAST path: 88 MB, prepacked weight planes, all buffers disjoint ----
    _Float16* peH = (_Float16*)(ws);                  // [0, 0.5M)
    _Float16* peL = (_Float16*)(ws + M1 / 2);         // [0.5, 1M)
    _Float16* xnH = (_Float16*)(ws + 1 * M1);         // [1, 3M)
    _Float16* xnL = (_Float16*)(ws + 3 * M1);         // [3, 5M)
    _Float16* wpH = (_Float16*)(ws + 5 * M1);         // [5, 6M)
    _Float16* wpL = (_Float16*)(ws + 6 * M1);         // [6, 7M)
    _Float16* wtH = (_Float16*)(ws + 7 * M1);         // [7, 8.5M)
    _Float16* wtL = (_Float16*)(ws + 8 * M1 + M1/2);  // [8.5, 10M)
    KpfH  = (u16*)(ws + 10 * M1);                     // [10, 10.5M)
    KpfL  = (u16*)(ws + 10 * M1 + M1 / 2);            // [10.5, 11M)
    posQH = (u16*)(ws + 11 * M1);                     // [11, 11.5M)
    posQL = (u16*)(ws + 11 * M1 + M1 / 2);            // [11.5, 12M)
    KtfH  = (u16*)(ws + 12 * M1);                     // [12, 14M)
    KtfL  = (u16*)(ws + 14 * M1);                     // [14, 16M)
    QH    = (u16*)(ws + 16 * M1);                     // [16, 18M)
    QL    = (u16*)(ws + 18 * M1);                     // [18, 20M)
    Vf    = (u16*)(ws + 20 * M1);                     // [20, 22M)

    prep_all<<<1280, 256, 0, stream>>>(x, gamma, beta, w_pos, w_tok,
        peH, peL, xnH, xnL, wpH, wpL, wtH, wtL);
    gemm16p<<<448, 256, 0, stream>>>(
        xnH, xnL, peH, peL, wtH, wtL, wpH, wpL,
        KtfH, KtfL, KpfH, KpfL, QH, QL, posQH, posQL, Vf,
        1.0f / 32.0f, IS / 32.0f, 1.0f / 32.0f);
  } else {
    // ---- FALLBACK: 68 MB, r12 path (B staged from fp32 originals) ----
    _Float16* peH = (_Float16*)(ws);                  // [0, 0.5M)
    _Float16* peL = (_Float16*)(ws + M1 / 2);         // [0.5, 1M)
    _Float16* xnH = (_Float16*)(ws + 1 * M1);         // [1, 3M)
    _Float16* xnL = (_Float16*)(ws + 3 * M1);         // [3, 5M)
    KpfH  = (u16*)(ws + 5 * M1);
    KpfL  = (u16*)(ws + 5 * M1 + M1 / 2);
    posQH = (u16*)(ws + 6 * M1);
    posQL = (u16*)(ws + 6 * M1 + M1 / 2);
    KtfH  = (u16*)(ws + 7 * M1);
    KtfL  = (u16*)(ws + 9 * M1);
    QH    = (u16*)(ws + 11 * M1);
    QL    = (u16*)(ws + 13 * M1);
    Vf    = (u16*)(ws + 15 * M1);

    prep_all<<<640, 256, 0, stream>>>(x, gamma, beta, w_pos, w_tok,
        peH, peL, xnH, xnL, (_Float16*)nullptr, (_Float16*)nullptr,
        (_Float16*)nullptr, (_Float16*)nullptr);
    gemm16m<<<448, 256, 0, stream>>>(
        xnH, xnL, peH, peL, w_tok, w_pos,
        KtfH, KtfL, KpfH, KpfL, QH, QL, posQH, posQL, Vf,
        1.0f / 32.0f, IS / 32.0f, 1.0f / 32.0f);
  }

  attn_mfma12<<<BB * NH * (SB / 128), 256, 0, stream>>>(
      KtfH, KtfL, KpfH, KpfL, QH, QL, posQH, posQL, Vf, bt, out);
}

// Round 9
// 243.245 us; speedup vs baseline: 1.0405x; 1.0405x over previous
//
#include <hip/hip_runtime.h>
#include <math.h>

#define SB 1024   // seq len
#define DM 1024   // d_model
#define BB 4      // batch
#define NH 16     // heads
#define DH 64     // head dim
#define ML 1024   // MAX_LEN

typedef __attribute__((ext_vector_type(8))) short short8;
typedef __attribute__((ext_vector_type(8))) _Float16 half8;
typedef __attribute__((ext_vector_type(4))) float f32x4;
typedef unsigned short u16;

__device__ __forceinline__ u16 f2bf(float x) {
  unsigned u = __float_as_uint(x);
  u += 0x7fffu + ((u >> 16) & 1u);
  return (u16)(u >> 16);
}
__device__ __forceinline__ float bf2f(u16 h) { return __uint_as_float((unsigned)h << 16); }

// async global->LDS, 16B per lane; lds base must be wave-uniform (HW adds lane*16)
__device__ __forceinline__ void async16(void* lds, const void* g) {
  __builtin_amdgcn_global_load_lds(
      (const __attribute__((address_space(1))) unsigned*)g,
      (__attribute__((address_space(3))) unsigned*)lds, 16, 0, 0);
}

// ======== S1: prep v2 (r17) — LDS-staged, coalesced-I/O packer ========
#define TPITCH 1028   // floats; %4==0 (16B align), %32==4 (bank spread)

__global__ __launch_bounds__(256, 4) void prep_all(
    const float* __restrict__ x, const float* __restrict__ gamma,
    const float* __restrict__ beta,
    const float* __restrict__ w_pos, const float* __restrict__ w_tok,
    _Float16* __restrict__ peH, _Float16* __restrict__ peL,
    _Float16* __restrict__ xnH, _Float16* __restrict__ xnL,
    _Float16* __restrict__ wpH, _Float16* __restrict__ wpL,
    _Float16* __restrict__ wtH, _Float16* __restrict__ wtL) {
  __shared__ float T[8 * TPITCH];      // 32.9 KB staging tile
  __shared__ float Sred[4][8][2];      // per-wave row stats (LN)

  int bid = blockIdx.x, t = threadIdx.x;
  int wv = t >> 6, lane = t & 63;

  int type, rt;
  const float* src = nullptr;
  _Float16 *dH, *dL;
  if (bid < 128)      { type = 0; rt = bid;       dH = peH; dL = peL; }
  else if (bid < 640) { type = 1; rt = bid - 128; src = x;     dH = xnH; dL = xnL; }
  else if (bid < 896) { type = 2; rt = bid - 640; src = w_pos; dH = wpH; dL = wpL; }
  else                { type = 2; rt = bid - 896; src = w_tok; dH = wtH; dL = wtL; }

  // ---- phase 1: fill T (coalesced: thread t covers cols t*4..+4 of each row)
  if (type == 0) {
    float div0 = exp2f((float)(t * 4)     * (-0.01297628162065376f));
    float div1 = exp2f((float)(t * 4 + 2) * (-0.01297628162065376f));
    #pragma unroll
    for (int i = 0; i < 8; ++i) {
      float p = (float)(rt * 8 + i);
      float a0 = p * div0, a1 = p * div1;
      float4 f;
      f.x = __sinf(a0); f.y = __cosf(a0);
      f.z = __sinf(a1); f.w = __cosf(a1);
      *(float4*)&T[i * TPITCH + t * 4] = f;
    }
  } else if (type == 1) {
    #pragma unroll
    for (int i = 0; i < 8; ++i) {
      float4 f = *(const float4*)(src + (size_t)(rt * 8 + i) * 1024 + t * 4);
      *(float4*)&T[i * TPITCH + t * 4] = f;
    }
  } else {
    #pragma unroll
    for (int i = 0; i < 8; ++i) {
      float4 f = *(const float4*)(src + (size_t)(rt * 8 + i) * 1024 + t * 4);
      f.x *= 32.f; f.y *= 32.f; f.z *= 32.f; f.w *= 32.f;
      *(float4*)&T[i * TPITCH + t * 4] = f;
    }
  }
  __syncthreads();

  // ---- phase 1b: LN row stats (thread: row t&7, 32-col chunk t>>3)
  if (type == 1) {
    int row = t & 7, cc = t >> 3;
    float s1 = 0.f, s2 = 0.f;
    #pragma unroll
    for (int i = 0; i < 8; ++i) {
      float4 f = *(const float4*)&T[row * TPITCH + cc * 32 + i * 4];
      s1 += f.x + f.y + f.z + f.w;
      s2 += f.x*f.x + f.y*f.y + f.z*f.z + f.w*f.w;
    }
    s1 += __shfl_xor(s1, 8, 64);  s2 += __shfl_xor(s2, 8, 64);
    s1 += __shfl_xor(s1, 16, 64); s2 += __shfl_xor(s2, 16, 64);
    s1 += __shfl_xor(s1, 32, 64); s2 += __shfl_xor(s2, 32, 64);
    if (lane < 8) { Sred[wv][lane][0] = s1; Sred[wv][lane][1] = s2; }
  }
  __syncthreads();

  // ---- phase 2: pack; lane l -> row l&7, col-group (l>>3)&3, kt-parity l>>5
  int row = lane & 7, gg = (lane >> 3) & 3, ktp = lane >> 5;
  float mu = 0.f, rs = 0.f;
  if (type == 1) {
    float s1 = Sred[0][row][0] + Sred[1][row][0] + Sred[2][row][0] + Sred[3][row][0];
    float s2 = Sred[0][row][1] + Sred[1][row][1] + Sred[2][row][1] + Sred[3][row][1];
    mu = s1 * (1.0f / 1024.0f);
    float var = s2 * (1.0f / 1024.0f) - mu * mu;
    rs = rsqrtf(var + 1e-5f);
  }
  int grow16 = rt >> 1;
  int rsub = (rt & 1) * 8 + row;
  #pragma unroll
  for (int q = 0; q < 4; ++q) {
    int kt = wv * 8 + q * 2 + ktp;
    int col = kt * 32 + gg * 8;
    float v[8];
    *(float4*)&v[0] = *(const float4*)&T[row * TPITCH + col];
    *(float4*)&v[4] = *(const float4*)&T[row * TPITCH + col + 4];
    if (type == 1) {
      float4 gp0 = *(const float4*)(gamma + col);
      float4 gp1 = *(const float4*)(gamma + col + 4);
      float4 bp0 = *(const float4*)(beta + col);
      float4 bp1 = *(const float4*)(beta + col + 4);
      v[0] = (v[0]-mu)*rs*gp0.x + bp0.x;  v[1] = (v[1]-mu)*rs*gp0.y + bp0.y;
      v[2] = (v[2]-mu)*rs*gp0.z + bp0.z;  v[3] = (v[3]-mu)*rs*gp0.w + bp0.w;
      v[4] = (v[4]-mu)*rs*gp1.x + bp1.x;  v[5] = (v[5]-mu)*rs*gp1.y + bp1.y;
      v[6] = (v[6]-mu)*rs*gp1.z + bp1.z;  v[7] = (v[7]-mu)*rs*gp1.w + bp1.w;
    }
    half8 hv, lv;
    #pragma unroll
    for (int j = 0; j < 8; ++j) {
      _Float16 h = (_Float16)v[j];
      hv[j] = h;
      lv[j] = (_Float16)(v[j] - (float)h);
    }
    size_t off = ((size_t)(grow16 * 32 + kt) * 64 + rsub + gg * 16) * 8;
    *(half8*)(dH + off) = hv;
    *(half8*)(dL + off) = lv;
  }
}

// ======== S2-fast: merged GEMM (r13 exact — best measured, 92us) ========
// NOTE (r14/r15 post-mortems): this kernel runs at ~794 TF = the 2-barrier
// K-step structure's ceiling. Explicit dbuf+counted-vmcnt (r14) = zero delta;
// staging B-lo via LDS (r15) = +17us regression. Do not re-attempt source-
// level pipelining on this structure.
__global__ __launch_bounds__(256, 2) void gemm16p(
    const _Float16* __restrict__ AtH, const _Float16* __restrict__ AtL,
    const _Float16* __restrict__ ApH, const _Float16* __restrict__ ApL,
    const _Float16* __restrict__ BtH, const _Float16* __restrict__ BtL,
    const _Float16* __restrict__ BpH, const _Float16* __restrict__ BpL,
    u16* __restrict__ KtfH, u16* __restrict__ KtfL,
    u16* __restrict__ KpfH, u16* __restrict__ KpfL,
    u16* __restrict__ QH, u16* __restrict__ QL,
    u16* __restrict__ pQH, u16* __restrict__ pQL,
    u16* __restrict__ vF, float sK, float sQ, float sV) {
  __shared__ _Float16 L[32 * 512];
  int t = threadIdx.x;
  int wv = t >> 6, lane = t & 63;
  int wm = wv >> 1, wn = wv & 1;
  int r16 = lane & 15, g = lane >> 4;

  int phys = blockIdx.x;
  int bid = (phys & 7) * 56 + (phys >> 3);   // XCD-chunked swizzle (448 = 8*56)
  bool isPos = (bid >= 384);
  int idx = isPos ? bid - 384 : bid;
  int n0, m0;
  const _Float16 *AH, *AL, *BH, *BL;
  if (isPos) { n0 = (idx & 7) * 256;  m0 = (idx >> 3) * 128;
               AH = ApH; AL = ApL; BH = BpH; BL = BpL; }
  else       { n0 = (idx % 12) * 256; m0 = (idx / 12) * 128;
               AH = AtH; AL = AtL; BH = BtH; BL = BtL; }
  int mt0 = m0 >> 4, nt0 = n0 >> 4;
  bool split = isPos || (n0 < 2048);   // tok V band (n0>=2048): hh-only

  f32x4 acc[4][8];
  #pragma unroll
  for (int i = 0; i < 4; ++i)
    #pragma unroll
    for (int j = 0; j < 8; ++j) acc[i][j] = (f32x4){0.f, 0.f, 0.f, 0.f};

  for (int kt = 0; kt < 32; ++kt) {
    __syncthreads();
    #pragma unroll
    for (int rd = 0; rd < 8; ++rd) {
      int ci = rd * 4 + wv;
      bool isAlo = (ci < 16) && (ci & 1);
      if (!split && isAlo) continue;         // wave-uniform skip
      const _Float16* src;
      if (ci < 16) {
        int mt = ci >> 1, pl = ci & 1;
        const _Float16* P = pl ? AL : AH;
        src = P + ((size_t)((mt0 + mt) * 32 + kt) * 64 + lane) * 8;
      } else {
        int nt = ci - 16;
        src = BH + ((size_t)((nt0 + nt) * 32 + kt) * 64 + lane) * 8;
      }
      async16(&L[ci * 512], src);
    }
    half8 blo[8];
    if (split) {
      #pragma unroll
      for (int j = 0; j < 8; ++j) {
        int ntg = nt0 + wn * 8 + j;
        blo[j] = *(const half8*)(BL + ((size_t)(ntg * 32 + kt) * 64 + lane) * 8);
      }
    }
    __syncthreads();

    half8 ah[4], al[4];
    #pragma unroll
    for (int i = 0; i < 4; ++i)
      ah[i] = *(const half8*)&L[(((wm * 4 + i) * 2 + 0) * 512) + lane * 8];
    if (split) {
      #pragma unroll
      for (int i = 0; i < 4; ++i)
        al[i] = *(const half8*)&L[(((wm * 4 + i) * 2 + 1) * 512) + lane * 8];
    }
    #pragma unroll
    for (int j = 0; j < 8; ++j) {
      half8 bh = *(const half8*)&L[((16 + wn * 8 + j) * 512) + lane * 8];
      #pragma unroll
      for (int i = 0; i < 4; ++i) {
        acc[i][j] = __builtin_amdgcn_mfma_f32_16x16x32_f16(ah[i], bh, acc[i][j], 0, 0, 0);
        if (split) {
          acc[i][j] = __builtin_amdgcn_mfma_f32_16x16x32_f16(al[i], bh, acc[i][j], 0, 0, 0);
          acc[i][j] = __builtin_amdgcn_mfma_f32_16x16x32_f16(ah[i], blo[j], acc[i][j], 0, 0, 0);
        }
      }
    }
  }

  int band = n0 >> 10;
  u16* fKH = isPos ? KpfH : KtfH;
  u16* fKL = isPos ? KpfL : KtfL;
  u16* qHo = isPos ? pQH  : QH;
  u16* qLo = isPos ? pQL  : QL;
  if (band == 1) {
    #pragma unroll
    for (int i = 0; i < 4; ++i)
      #pragma unroll
      for (int j = 0; j < 8; ++j) {
        int lc = (n0 & 1023) + wn * 128 + j * 16 + r16;
        #pragma unroll
        for (int reg = 0; reg < 4; ++reg) {
          int row = m0 + wm * 64 + i * 16 + g * 4 + reg;
          float cv = acc[i][j][reg] * sQ;
          u16 hi = f2bf(cv);
          qHo[(size_t)row * 1024 + lc] = hi;
          qLo[(size_t)row * 1024 + lc] = f2bf(cv - bf2f(hi));
        }
      }
  } else if (band == 0) {
    #pragma unroll
    for (int i = 0; i < 4; ++i)
      #pragma unroll
      for (int j = 0; j < 8; ++j) {
        int colg = n0 + wn * 128 + j * 16 + r16;   // < 1024
        int h = colg >> 6, dc = colg & 63;
        #pragma unroll
        for (int reg = 0; reg < 4; ++reg) {
          int row = m0 + wm * 64 + i * 16 + g * 4 + reg;
          int bhK = (row >> 10) * NH + h;
          size_t a = ((size_t)((bhK * 64 + ((row & 1023) >> 4)) * 2 + (dc >> 5)) << 9)
                   + ((row & 15) + 16 * ((dc >> 3) & 3)) * 8 + (dc & 7);
          float cv = acc[i][j][reg] * sK;
          u16 hi = f2bf(cv);
          fKH[a] = hi;
          fKL[a] = f2bf(cv - bf2f(hi));
        }
      }
  } else {
    #pragma unroll
    for (int i = 0; i < 4; ++i)
      #pragma unroll
      for (int j = 0; j < 8; ++j) {
        int colg = (n0 & 1023) + wn * 128 + j * 16 + r16;
        int h = colg >> 6, dc = colg & 63;
        #pragma unroll
        for (int reg = 0; reg < 4; ++reg) {
          int row = m0 + wm * 64 + i * 16 + g * 4 + reg;
          int s = row & 1023;
          size_t a = ((size_t)((((row >> 10) * NH + h) * 32 + (s >> 5)) * 4 + (dc >> 4)) << 9)
                   + ((s >> 3) & 3) * 128 + (s & 7) + (dc & 15) * 8;
          vF[a] = f2bf(acc[i][j][reg] * sV);
        }
      }
  }
}

// ======== S2-fallback: r12 merged GEMM, B staged from fp32 originals ========
__global__ __launch_bounds__(256, 2) void gemm16m(
    const _Float16* __restrict__ AtH, const _Float16* __restrict__ AtL,
    const _Float16* __restrict__ ApH, const _Float16* __restrict__ ApL,
    const float* __restrict__ Wt, const float* __restrict__ Wp,
    u16* __restrict__ KtfH, u16* __restrict__ KtfL,
    u16* __restrict__ KpfH, u16* __restrict__ KpfL,
    u16* __restrict__ QH, u16* __restrict__ QL,
    u16* __restrict__ pQH, u16* __restrict__ pQL,
    u16* __restrict__ vF, float sK, float sQ, float sV) {
  __shared__ _Float16 L[48 * 512];
  int t = threadIdx.x;
  int wv = t >> 6, lane = t & 63;
  int wm = wv >> 1, wn = wv & 1;
  int r16 = lane & 15, g = lane >> 4;

  int phys = blockIdx.x;
  int bid = (phys & 7) * 56 + (phys >> 3);   // XCD-chunked swizzle
  bool isPos = (bid >= 384);
  int idx = isPos ? bid - 384 : bid;
  int n0, m0;
  const _Float16 *AH, *AL;
  const float* W;
  if (isPos) { n0 = (idx & 7) * 256;  m0 = (idx >> 3) * 128; AH = ApH; AL = ApL; W = Wp; }
  else       { n0 = (idx % 12) * 256; m0 = (idx / 12) * 128; AH = AtH; AL = AtL; W = Wt; }
  int mt0 = m0 >> 4, nt0 = n0 >> 4;
  bool split = isPos || (n0 < 2048);

  f32x4 acc[4][8];
  #pragma unroll
  for (int i = 0; i < 4; ++i)
    #pragma unroll
    for (int j = 0; j < 8; ++j) acc[i][j] = (f32x4){0.f, 0.f, 0.f, 0.f};

  for (int kt = 0; kt < 32; ++kt) {
    __syncthreads();
    #pragma unroll
    for (int rd = 0; rd < 4; ++rd) {
      int ci = rd * 4 + wv;
      int mt = ci >> 1, pl = ci & 1;
      if (!split && pl) continue;
      const _Float16* src = (pl ? AL : AH)
          + ((size_t)((mt0 + mt) * 32 + kt) * 64 + lane) * 8;
      async16(&L[ci * 512], src);
    }
    #pragma unroll
    for (int tt = 0; tt < 4; ++tt) {
      int nt = wv * 4 + tt;
      const float* wsrc = W + (size_t)((nt0 + nt) * 16 + r16) * 1024 + kt * 32 + g * 8;
      float4 w0 = *(const float4*)wsrc;
      float4 w1 = *(const float4*)(wsrc + 4);
      float wvv[8] = {w0.x, w0.y, w0.z, w0.w, w1.x, w1.y, w1.z, w1.w};
      half8 hv, lv;
      #pragma unroll
      for (int j = 0; j < 8; ++j) {
        float xx = wvv[j] * 32.0f;
        _Float16 h = (_Float16)xx;
        hv[j] = h;
        lv[j] = (_Float16)(xx - (float)h);
      }
      *(half8*)&L[(16 + nt) * 512 + lane * 8] = hv;
      if (split) *(half8*)&L[(32 + nt) * 512 + lane * 8] = lv;
    }
    __syncthreads();

    half8 ah[4], al[4];
    #pragma unroll
    for (int i = 0; i < 4; ++i)
      ah[i] = *(const half8*)&L[(((wm * 4 + i) * 2 + 0) * 512) + lane * 8];
    if (split) {
      #pragma unroll
      for (int i = 0; i < 4; ++i)
        al[i] = *(const half8*)&L[(((wm * 4 + i) * 2 + 1) * 512) + lane * 8];
    }
    #pragma unroll
    for (int j = 0; j < 8; ++j) {
      half8 bh = *(const half8*)&L[((16 + wn * 8 + j) * 512) + lane * 8];
      #pragma unroll
      for (int i = 0; i < 4; ++i) {
        acc[i][j] = __builtin_amdgcn_mfma_f32_16x16x32_f16(ah[i], bh, acc[i][j], 0, 0, 0);
        if (split) {
          half8 bl = *(const half8*)&L[((32 + wn * 8 + j) * 512) + lane * 8];
          acc[i][j] = __builtin_amdgcn_mfma_f32_16x16x32_f16(al[i], bh, acc[i][j], 0, 0, 0);
          acc[i][j] = __builtin_amdgcn_mfma_f32_16x16x32_f16(ah[i], bl, acc[i][j], 0, 0, 0);
        }
      }
    }
  }

  int band = n0 >> 10;
  u16* fKH = isPos ? KpfH : KtfH;
  u16* fKL = isPos ? KpfL : KtfL;
  u16* qHo = isPos ? pQH  : QH;
  u16* qLo = isPos ? pQL  : QL;
  if (band == 1) {
    #pragma unroll
    for (int i = 0; i < 4; ++i)
      #pragma unroll
      for (int j = 0; j < 8; ++j) {
        int lc = (n0 & 1023) + wn * 128 + j * 16 + r16;
        #pragma unroll
        for (int reg = 0; reg < 4; ++reg) {
          int row = m0 + wm * 64 + i * 16 + g * 4 + reg;
          float cv = acc[i][j][reg] * sQ;
          u16 hi = f2bf(cv);
          qHo[(size_t)row * 1024 + lc] = hi;
          qLo[(size_t)row * 1024 + lc] = f2bf(cv - bf2f(hi));
        }
      }
  } else if (band == 0) {
    #pragma unroll
    for (int i = 0; i < 4; ++i)
      #pragma unroll
      for (int j = 0; j < 8; ++j) {
        int colg = n0 + wn * 128 + j * 16 + r16;
        int h = colg >> 6, dc = colg & 63;
        #pragma unroll
        for (int reg = 0; reg < 4; ++reg) {
          int row = m0 + wm * 64 + i * 16 + g * 4 + reg;
          int bhK = (row >> 10) * NH + h;
          size_t a = ((size_t)((bhK * 64 + ((row & 1023) >> 4)) * 2 + (dc >> 5)) << 9)
                   + ((row & 15) + 16 * ((dc >> 3) & 3)) * 8 + (dc & 7);
          float cv = acc[i][j][reg] * sK;
          u16 hi = f2bf(cv);
          fKH[a] = hi;
          fKL[a] = f2bf(cv - bf2f(hi));
        }
      }
  } else {
    #pragma unroll
    for (int i = 0; i < 4; ++i)
      #pragma unroll
      for (int j = 0; j < 8; ++j) {
        int colg = (n0 & 1023) + wn * 128 + j * 16 + r16;
        int h = colg >> 6, dc = colg & 63;
        #pragma unroll
        for (int reg = 0; reg < 4; ++reg) {
          int row = m0 + wm * 64 + i * 16 + g * 4 + reg;
          int s = row & 1023;
          size_t a = ((size_t)((((row >> 10) * NH + h) * 32 + (s >> 5)) * 4 + (dc >> 4)) << 9)
                   + ((s >> 3) & 3) * 128 + (s & 7) + (dc & 15) * 8;
          vF[a] = f2bf(acc[i][j][reg] * sV);
        }
      }
  }
}

// ======== S3: MFMA flash attention (r13 structure + bias-identity) ========
// r18 post-mortem: kp-from-global (+14us) falsified the LDS-pipe theory; the
// r13 single-buffer structure is the measured local optimum (r14 +5, r18 +14).
// Only surviving r18 piece: bias[1][nt] == bias[0][nt-1] (pure algebra,
// 32 -> 20 scalar biasL reads per ktr per thread).
__global__ __launch_bounds__(256, 2) void attn_mfma10(
    const u16* __restrict__ KtfH, const u16* __restrict__ KtfL,
    const u16* __restrict__ KpfH, const u16* __restrict__ KpfL,
    const u16* __restrict__ QHg, const u16* __restrict__ QLg,
    const u16* __restrict__ pQH, const u16* __restrict__ pQL,
    const u16* __restrict__ Vf,
    const float* __restrict__ bt,
    float* __restrict__ out) {
  __shared__ u16 Klds[5 * 4096];     // 40 KB: [tokH|tokL|posH|posL|V] for one ktr
  __shared__ float biasL[2 * ML];    // 8 KB
  __shared__ u16 Pb[4][16 * 72];     // 9 KB: per-wave P staging, one cc at a time

  int phys = blockIdx.x;
  int bid = (phys & 7) * 64 + (phys >> 3);   // XCD-chunked (512 = 8*64, bijective)
  int qt = bid & 7;
  int bh = bid >> 3;
  int b = bh >> 4, h = bh & 15;
  int q0 = qt * 128;
  int t = threadIdx.x;
  int wv = t >> 6, lane = t & 63;
  int g = lane >> 4, r16 = lane & 15;
  int lo = lane * 8;                 // this lane's 16B frag offset (u16 units)

  #pragma unroll
  for (int k = 0; k < 8; ++k)
    biasL[t + k * 256] = bt[(size_t)(t + k * 256) * NH + h];

  short8 qhi[2][4], qlo[2][4];
  #pragma unroll
  for (int cc = 0; cc < 2; ++cc) {
    int qrow = q0 + wv * 32 + cc * 16 + r16;
    #pragma unroll
    for (int c = 0; c < 4; ++c) {
      if (c < 2) {
        size_t off = (size_t)(b * SB + qrow) * 1024 + h * DH + c * 32 + g * 8;
        qhi[cc][c] = *(const short8*)(QHg + off);
        qlo[cc][c] = *(const short8*)(QLg + off);
      } else {
        size_t off = (size_t)qrow * 1024 + h * DH + (c - 2) * 32 + g * 8;
        qhi[cc][c] = *(const short8*)(pQH + off);
        qlo[cc][c] = *(const short8*)(pQL + off);
      }
    }
  }

  f32x4 O[2][4];
  #pragma unroll
  for (int cc = 0; cc < 2; ++cc)
    #pragma unroll
    for (int dt = 0; dt < 4; ++dt) O[cc][dt] = (f32x4){0.f, 0.f, 0.f, 0.f};
  float m_run[2][4], l_run[2][4];
  #pragma unroll
  for (int cc = 0; cc < 2; ++cc)
    #pragma unroll
    for (int reg = 0; reg < 4; ++reg) { m_run[cc][reg] = -3e38f; l_run[cc][reg] = 0.f; }

  int qb0 = q0 + wv * 32 + g * 4;
  // per-ktr chunk bases (each chunk is a contiguous 4096-u16 region)
  const u16* ktHb = KtfH + (size_t)(bh * 64) * 1024;
  const u16* ktLb = KtfL + (size_t)(bh * 64) * 1024;
  const u16* kpHb = KpfH + (size_t)(h * 64) * 1024;
  const u16* kpLb = KpfL + (size_t)(h * 64) * 1024;
  const u16* vb   = Vf   + (size_t)(bh * 32) * 2048;
  int bb = ML + r16 - qb0;

  for (int ktr = 0; ktr < 16; ++ktr) {
    __syncthreads();   // prev-iter Klds reads done (iter0: biasL ready)

    // stage this ktr's K/V: 5 chunks x 8 KB; each wave covers pieces wv, wv+4
    {
      int p0 = wv * 512, p1 = (wv + 4) * 512;
      async16(&Klds[0 * 4096 + p0], ktHb + p0 + lo);
      async16(&Klds[0 * 4096 + p1], ktHb + p1 + lo);
      async16(&Klds[1 * 4096 + p0], ktLb + p0 + lo);
      async16(&Klds[1 * 4096 + p1], ktLb + p1 + lo);
      async16(&Klds[2 * 4096 + p0], kpHb + p0 + lo);
      async16(&Klds[2 * 4096 + p1], kpHb + p1 + lo);
      async16(&Klds[3 * 4096 + p0], kpLb + p0 + lo);
      async16(&Klds[3 * 4096 + p1], kpLb + p1 + lo);
      async16(&Klds[4 * 4096 + p0], vb + p0 + lo);
      async16(&Klds[4 * 4096 + p1], vb + p1 + lo);
    }

    // bias regs overlap the staging latency; only 20 distinct values
    // (bias[1][nt] == bias[0][nt-1] for nt >= 1)
    float bias0[4][4], bias1[4];
    #pragma unroll
    for (int nt = 0; nt < 4; ++nt)
      #pragma unroll
      for (int reg = 0; reg < 4; ++reg)
        bias0[nt][reg] = biasL[bb + nt * 16 - reg];
    #pragma unroll
    for (int reg = 0; reg < 4; ++reg)
      bias1[reg] = biasL[bb - 16 - reg];

    asm volatile("s_waitcnt vmcnt(0)" ::: "memory");
    __syncthreads();   // staging visible to all waves

    f32x4 S[2][4];
    #pragma unroll
    for (int nt = 0; nt < 4; ++nt) {
      f32x4 a0 = (f32x4){0.f, 0.f, 0.f, 0.f};
      f32x4 a1 = (f32x4){0.f, 0.f, 0.f, 0.f};
      #pragma unroll
      for (int c = 0; c < 4; ++c) {
        int ch = (c < 2) ? 0 : 2;          // tok chunks 0/1, pos chunks 2/3
        int co = c & 1;
        short8 bhi = *(const short8*)&Klds[(ch + 0) * 4096 + nt * 1024 + co * 512 + lo];
        short8 blo = *(const short8*)&Klds[(ch + 1) * 4096 + nt * 1024 + co * 512 + lo];
        a0 = __builtin_amdgcn_mfma_f32_16x16x32_bf16(qhi[0][c], bhi, a0, 0, 0, 0);
        a1 = __builtin_amdgcn_mfma_f32_16x16x32_bf16(qhi[1][c], bhi, a1, 0, 0, 0);
        a0 = __builtin_amdgcn_mfma_f32_16x16x32_bf16(qlo[0][c], bhi, a0, 0, 0, 0);
        a1 = __builtin_amdgcn_mfma_f32_16x16x32_bf16(qlo[1][c], bhi, a1, 0, 0, 0);
        a0 = __builtin_amdgcn_mfma_f32_16x16x32_bf16(qhi[0][c], blo, a0, 0, 0, 0);
        a1 = __builtin_amdgcn_mfma_f32_16x16x32_bf16(qhi[1][c], blo, a1, 0, 0, 0);
      }
      S[0][nt] = a0; S[1][nt] = a1;
    }

    short8 vfrag[2][4];
    #pragma unroll
    for (int kc = 0; kc < 2; ++kc)
      #pragma unroll
      for (int dt = 0; dt < 4; ++dt)
        vfrag[kc][dt] = *(const short8*)&Klds[4 * 4096 + (kc * 4 + dt) * 512 + lo];

    #pragma unroll
    for (int nt = 0; nt < 4; ++nt)
      #pragma unroll
      for (int reg = 0; reg < 4; ++reg) {
        S[0][nt][reg] += bias0[nt][reg];
        S[1][nt][reg] += (nt == 0) ? bias1[reg] : bias0[nt - 1][reg];
      }

    float tm[2][4], al[2][4];
    #pragma unroll
    for (int cc = 0; cc < 2; ++cc)
      #pragma unroll
      for (int reg = 0; reg < 4; ++reg)
        tm[cc][reg] = fmaxf(fmaxf(S[cc][0][reg], S[cc][1][reg]),
                            fmaxf(S[cc][2][reg], S[cc][3][reg]));
    #pragma unroll
    for (int off = 1; off < 16; off <<= 1)
      #pragma unroll
      for (int cc = 0; cc < 2; ++cc)
        #pragma unroll
        for (int reg = 0; reg < 4; ++reg)
          tm[cc][reg] = fmaxf(tm[cc][reg], __shfl_xor(tm[cc][reg], off, 64));
    #pragma unroll
    for (int cc = 0; cc < 2; ++cc)
      #pragma unroll
      for (int reg = 0; reg < 4; ++reg) {
        float mn = fmaxf(m_run[cc][reg], tm[cc][reg]);
        al[cc][reg] = __expf(m_run[cc][reg] - mn);
        m_run[cc][reg] = mn;
      }
    float ts[2][4] = {{0.f, 0.f, 0.f, 0.f}, {0.f, 0.f, 0.f, 0.f}};
    #pragma unroll
    for (int cc = 0; cc < 2; ++cc)
      #pragma unroll
      for (int nt = 0; nt < 4; ++nt)
        #pragma unroll
        for (int reg = 0; reg < 4; ++reg) {
          float p = __expf(S[cc][nt][reg] - m_run[cc][reg]);
          S[cc][nt][reg] = p;
          ts[cc][reg] += p;
        }
    #pragma unroll
    for (int cc = 0; cc < 2; ++cc)
      #pragma unroll
      for (int reg = 0; reg < 4; ++reg)
        l_run[cc][reg] = l_run[cc][reg] * al[cc][reg] + ts[cc][reg];
    #pragma unroll
    for (int cc = 0; cc < 2; ++cc)
      #pragma unroll
      for (int dt = 0; dt < 4; ++dt)
        #pragma unroll
        for (int reg = 0; reg < 4; ++reg)
          O[cc][dt][reg] *= al[cc][reg];

    // P staging + PV, one cc at a time (halves Pb LDS; per-wave in-order DS
    // pipeline makes write->read->rewrite safe without barriers)
    #pragma unroll
    for (int cc = 0; cc < 2; ++cc) {
      u16* pb = Pb[wv];
      #pragma unroll
      for (int nt = 0; nt < 4; ++nt)
        #pragma unroll
        for (int reg = 0; reg < 4; ++reg)
          pb[(g * 4 + reg) * 72 + nt * 16 + r16] = f2bf(S[cc][nt][reg]);
      #pragma unroll
      for (int kc = 0; kc < 2; ++kc) {
        short8 pa = *(const short8*)&Pb[wv][r16 * 72 + kc * 32 + g * 8];
        #pragma unroll
        for (int dt = 0; dt < 4; ++dt)
          O[cc][dt] = __builtin_amdgcn_mfma_f32_16x16x32_bf16(pa, vfrag[kc][dt], O[cc][dt], 0, 0, 0);
      }
    }

    ktHb += 4096; ktLb += 4096; kpHb += 4096; kpLb += 4096;
    vb += 4096; bb += 64;
  }

  #pragma unroll
  for (int off = 1; off < 16; off <<= 1)
    #pragma unroll
    for (int cc = 0; cc < 2; ++cc)
      #pragma unroll
      for (int reg = 0; reg < 4; ++reg)
        l_run[cc][reg] += __shfl_xor(l_run[cc][reg], off, 64);
  #pragma unroll
  for (int cc = 0; cc < 2; ++cc)
    #pragma unroll
    for (int reg = 0; reg < 4; ++reg) l_run[cc][reg] = 1.0f / l_run[cc][reg];
  #pragma unroll
  for (int cc = 0; cc < 2; ++cc)
    #pragma unroll
    for (int dt = 0; dt < 4; ++dt)
      #pragma unroll
      for (int reg = 0; reg < 4; ++reg)
        out[(size_t)(b * SB + qb0 + cc * 16 + reg) * DM + h * DH + dt * 16 + r16] =
            O[cc][dt][reg] * l_run[cc][reg];
}

extern "C" void kernel_launch(void* const* d_in, const int* in_sizes, int n_in,
                              void* d_out, int out_size, void* d_ws, size_t ws_size,
                              hipStream_t stream) {
  const float* x     = (const float*)d_in[0];
  const float* gamma = (const float*)d_in[1];
  const float* beta  = (const float*)d_in[2];
  const float* w_pos = (const float*)d_in[3];
  const float* w_tok = (const float*)d_in[4];
  const float* bt    = (const float*)d_in[5];
  float* out = (float*)d_out;
  float* ws  = (float*)d_ws;
  const size_t M1 = 1u << 20;
  const float IS = 11.313708498984761f;  // sqrt(2*dh)

  u16 *KtfH, *KtfL, *KpfH, *KpfL, *QH, *QL, *posQH, *posQL, *Vf;

  if (ws_size >= 22 * M1 * 4) {
    // ---- FAST path: 88 MB, prepacked weight planes, all buffers disjoint ----
    _Float16* peH = (_Float16*)(ws);                  // [0, 0.5M)
    _Float16* peL = (_Float16*)(ws + M1 / 2);         // [0.5, 1M)
    _Float16* xnH = (_Float16*)(ws + 1 * M1);         // [1, 3M)
    _Float16* xnL = (_Float16*)(ws + 3 * M1);         // [3, 5M)
    _Float16* wpH = (_Float16*)(ws + 5 * M1);         // [5, 6M)
    _Float16* wpL = (_Float16*)(ws + 6 * M1);         // [6, 7M)
    _Float16* wtH = (_Float16*)(ws + 7 * M1);         // [7, 8.5M)
    _Float16* wtL = (_Float16*)(ws + 8 * M1 + M1/2);  // [8.5, 10M)
    KpfH  = (u16*)(ws + 10 * M1);                     // [10, 10.5M)
    KpfL  = (u16*)(ws + 10 * M1 + M1 / 2);            // [10.5, 11M)
    posQH = (u16*)(ws + 11 * M1);                     // [11, 11.5M)
    posQL = (u16*)(ws + 11 * M1 + M1 / 2);            // [11.5, 12M)
    KtfH  = (u16*)(ws + 12 * M1);                     // [12, 14M)
    KtfL  = (u16*)(ws + 14 * M1);                     // [14, 16M)
    QH    = (u16*)(ws + 16 * M1);                     // [16, 18M)
    QL    = (u16*)(ws + 18 * M1);                     // [18, 20M)
    Vf    = (u16*)(ws + 20 * M1);                     // [20, 22M)

    prep_all<<<1280, 256, 0, stream>>>(x, gamma, beta, w_pos, w_tok,
        peH, peL, xnH, xnL, wpH, wpL, wtH, wtL);
    gemm16p<<<448, 256, 0, stream>>>(
        xnH, xnL, peH, peL, wtH, wtL, wpH, wpL,
        KtfH, KtfL, KpfH, KpfL, QH, QL, posQH, posQL, Vf,
        1.0f / 32.0f, IS / 32.0f, 1.0f / 32.0f);
  } else {
    // ---- FALLBACK: 68 MB, r12 path (B staged from fp32 originals) ----
    _Float16* peH = (_Float16*)(ws);                  // [0, 0.5M)
    _Float16* peL = (_Float16*)(ws + M1 / 2);         // [0.5, 1M)
    _Float16* xnH = (_Float16*)(ws + 1 * M1);         // [1, 3M)
    _Float16* xnL = (_Float16*)(ws + 3 * M1);         // [3, 5M)
    KpfH  = (u16*)(ws + 5 * M1);
    KpfL  = (u16*)(ws + 5 * M1 + M1 / 2);
    posQH = (u16*)(ws + 6 * M1);
    posQL = (u16*)(ws + 6 * M1 + M1 / 2);
    KtfH  = (u16*)(ws + 7 * M1);
    KtfL  = (u16*)(ws + 9 * M1);
    QH    = (u16*)(ws + 11 * M1);
    QL    = (u16*)(ws + 13 * M1);
    Vf    = (u16*)(ws + 15 * M1);

    prep_all<<<640, 256, 0, stream>>>(x, gamma, beta, w_pos, w_tok,
        peH, peL, xnH, xnL, (_Float16*)nullptr, (_Float16*)nullptr,
        (_Float16*)nullptr, (_Float16*)nullptr);
    gemm16m<<<448, 256, 0, stream>>>(
        xnH, xnL, peH, peL, w_tok, w_pos,
        KtfH, KtfL, KpfH, KpfL, QH, QL, posQH, posQL, Vf,
        1.0f / 32.0f, IS / 32.0f, 1.0f / 32.0f);
  }

  attn_mfma10<<<BB * NH * (SB / 128), 256, 0, stream>>>(
      KtfH, KtfL, KpfH, KpfL, QH, QL, posQH, posQL, Vf, bt, out);
}